// Round 1
// baseline (170.562 us; speedup 1.0000x reference)
//
#include <hip/hip_runtime.h>
#include <math.h>

#define NB 10
#define HH 100

// ---------------------------------------------------------------------------
// Sizes (fixed by the problem): B=8, N1=N2=32 -> N=64, C=64, H=100, R=10
// ws layout (floats):
//   xcat    [8][64][64]        = 32768
//   rmat    [8][64][64]        = 32768
//   h2      [8*64*64][100]     = 3276800   (pair-major, h contiguous)
//   M       [8][6400(bh)][64]  = 3276800   (bh = b*100+h)
//   partial [8][8(kc)][64][64] = 262144
// total 6,881,280 floats = 27.5 MB
// ---------------------------------------------------------------------------

__global__ __launch_bounds__(64) void prep_kernel(
    const float* __restrict__ in1, const float* __restrict__ in2,
    const float* __restrict__ xyz1, const float* __restrict__ xyz2,
    float* __restrict__ xcat, float* __restrict__ rmat)
{
    int zn = blockIdx.x;            // 0..511  (z*64 + n)
    int z = zn >> 6, n = zn & 63;
    int t = threadIdx.x;            // 0..63

    // concat x
    xcat[zn * 64 + t] = (n < 32) ? in1[(z * 32 + n) * 64 + t]
                                 : in2[(z * 32 + (n - 32)) * 64 + t];

    // pairwise distance r[z][n][t]
    float ax, ay, az, bx, by, bz;
    if (n < 32) { const float* p = xyz1 + (z * 32 + n) * 3;        ax = p[0]; ay = p[1]; az = p[2]; }
    else        { const float* p = xyz2 + (z * 32 + (n - 32)) * 3; ax = p[0]; ay = p[1]; az = p[2]; }
    if (t < 32) { const float* p = xyz1 + (z * 32 + t) * 3;        bx = p[0]; by = p[1]; bz = p[2]; }
    else        { const float* p = xyz2 + (z * 32 + (t - 32)) * 3; bx = p[0]; by = p[1]; bz = p[2]; }
    float dx = ax - bx, dy = ay - by, dz = az - bz;
    rmat[zn * 64 + t] = sqrtf(dx * dx + dy * dy + dz * dz + 1e-12f);
}

// radial MLP: r -> cosine basis -> silu(b@w1/sqrt(10)) -> silu(h1@w2/10) -> h2
// 16 pairs per block; w1+w2 staged in LDS.
__global__ __launch_bounds__(256) void radial_kernel(
    const float* __restrict__ rmat,
    const float* __restrict__ w1, const float* __restrict__ w2,
    float* __restrict__ h2out)
{
    __shared__ float s_w1[NB * HH];     // 1000
    __shared__ float s_w2[HH * HH];     // 10000
    __shared__ float s_basis[16][NB];
    __shared__ float s_h1[16][HH];

    int tid = threadIdx.x;
    for (int i = tid; i < NB * HH; i += 256) s_w1[i] = w1[i];
    for (int i = tid; i < HH * HH; i += 256) s_w2[i] = w2[i];

    int pbase = blockIdx.x * 16;
    const float STEP = 10.0f / 9.0f;
    const float HALF_PI = 1.57079632679489662f;

    if (tid < 16 * NB) {
        int p = tid / NB, j = tid % NB;
        float r = rmat[pbase + p];
        float u = (r - (float)j * STEP) / STEP * HALF_PI;
        float c = __cosf(u);
        s_basis[p][j] = (fabsf(u) < HALF_PI) ? c * c : 0.0f;
    }
    __syncthreads();

    const float inv_sqrt10 = 0.31622776601683794f;
    for (int task = tid; task < 16 * HH; task += 256) {
        int p = task / HH, k = task % HH;
        float acc = 0.f;
        #pragma unroll
        for (int j = 0; j < NB; ++j) acc += s_basis[p][j] * s_w1[j * HH + k];
        acc *= inv_sqrt10;
        float sg = 1.0f / (1.0f + __expf(-acc));
        s_h1[p][k] = acc * sg;
    }
    __syncthreads();

    for (int task = tid; task < 16 * HH; task += 256) {
        int p = task / HH, k2 = task % HH;
        float acc = 0.f;
        #pragma unroll 4
        for (int k = 0; k < HH; ++k) acc += s_h1[p][k] * s_w2[k * HH + k2];
        acc *= 0.1f;
        float sg = 1.0f / (1.0f + __expf(-acc));
        h2out[(size_t)(pbase + p) * HH + k2] = acc * sg;
    }
}

// M[z][b*100+h][o] = sum_i w3[h][o*64+i] * xcat[z][b][i]
// grid: (64 zb-groups of 8, 4 ho-quarters of 1600), 256 threads
__global__ __launch_bounds__(256) void kernel_M(
    const float* __restrict__ xcat, const float* __restrict__ w3,
    float* __restrict__ Mout)
{
    __shared__ float s_x[8][64];
    int tid = threadIdx.x;
    int zb0 = blockIdx.x * 8;
    for (int i = tid; i < 512; i += 256) s_x[i >> 6][i & 63] = xcat[zb0 * 64 + i];
    __syncthreads();

    int ho_end = blockIdx.y * 1600 + 1600;
    for (int ho = blockIdx.y * 1600 + tid; ho < ho_end; ho += 256) {
        int h = ho >> 6, o = ho & 63;
        const float4* wrow = (const float4*)(w3 + (size_t)h * 4096 + o * 64);
        float acc0 = 0, acc1 = 0, acc2 = 0, acc3 = 0, acc4 = 0, acc5 = 0, acc6 = 0, acc7 = 0;
        #pragma unroll
        for (int i4 = 0; i4 < 16; ++i4) {
            float4 w = wrow[i4];
            int i = i4 * 4;
            acc0 += w.x * s_x[0][i] + w.y * s_x[0][i + 1] + w.z * s_x[0][i + 2] + w.w * s_x[0][i + 3];
            acc1 += w.x * s_x[1][i] + w.y * s_x[1][i + 1] + w.z * s_x[1][i + 2] + w.w * s_x[1][i + 3];
            acc2 += w.x * s_x[2][i] + w.y * s_x[2][i + 1] + w.z * s_x[2][i + 2] + w.w * s_x[2][i + 3];
            acc3 += w.x * s_x[3][i] + w.y * s_x[3][i + 1] + w.z * s_x[3][i + 2] + w.w * s_x[3][i + 3];
            acc4 += w.x * s_x[4][i] + w.y * s_x[4][i + 1] + w.z * s_x[4][i + 2] + w.w * s_x[4][i + 3];
            acc5 += w.x * s_x[5][i] + w.y * s_x[5][i + 1] + w.z * s_x[5][i + 2] + w.w * s_x[5][i + 3];
            acc6 += w.x * s_x[6][i] + w.y * s_x[6][i + 1] + w.z * s_x[6][i + 2] + w.w * s_x[6][i + 3];
            acc7 += w.x * s_x[7][i] + w.y * s_x[7][i + 1] + w.z * s_x[7][i + 2] + w.w * s_x[7][i + 3];
        }
        // Mout[(zb0+zb)*6400 + h*64 + o]; note bh = b*100+h ordering handled by caller layout:
        // row index within z is (b*100+h), and zb0+zb enumerates (z*64+b).
        size_t base = (size_t)ho;  // h*64+o
        Mout[(size_t)(zb0 + 0) * 6400 + base] = acc0;
        Mout[(size_t)(zb0 + 1) * 6400 + base] = acc1;
        Mout[(size_t)(zb0 + 2) * 6400 + base] = acc2;
        Mout[(size_t)(zb0 + 3) * 6400 + base] = acc3;
        Mout[(size_t)(zb0 + 4) * 6400 + base] = acc4;
        Mout[(size_t)(zb0 + 5) * 6400 + base] = acc5;
        Mout[(size_t)(zb0 + 6) * 6400 + base] = acc6;
        Mout[(size_t)(zb0 + 7) * 6400 + base] = acc7;
    }
}

// y[z][a][o] partials: contraction over bh chunks.
// grid: (z=8, a-tiles=4 of 16 rows, k-chunks=8 of 800 bh), 256 threads
__global__ __launch_bounds__(256) void kernel_Y(
    const float* __restrict__ h2, const float* __restrict__ M,
    float* __restrict__ partial)
{
    __shared__ float s_M[100][64];   // 25.6 KB
    __shared__ float s_h2[16][100];  // 6.4 KB

    int z = blockIdx.x, at = blockIdx.y, kc = blockIdx.z;
    int tid = threadIdx.x;
    int o = tid & 63;
    int ag = tid >> 6;   // 0..3 -> handles 4 a-rows each

    float acc0 = 0, acc1 = 0, acc2 = 0, acc3 = 0;

    for (int sc = 0; sc < 8; ++sc) {
        int bh0 = kc * 800 + sc * 100;
        __syncthreads();
        for (int idx = tid; idx < 6400; idx += 256)
            s_M[idx >> 6][idx & 63] = M[(size_t)z * 409600 + (size_t)bh0 * 64 + idx];
        for (int idx = tid; idx < 1600; idx += 256) {
            int a = idx / 100, c = idx % 100;
            s_h2[a][c] = h2[(size_t)(z * 64 + at * 16 + a) * 6400 + bh0 + c];
        }
        __syncthreads();
        int a0 = ag * 4;
        #pragma unroll 4
        for (int c = 0; c < 100; ++c) {
            float mv = s_M[c][o];
            acc0 += s_h2[a0 + 0][c] * mv;
            acc1 += s_h2[a0 + 1][c] * mv;
            acc2 += s_h2[a0 + 2][c] * mv;
            acc3 += s_h2[a0 + 3][c] * mv;
        }
    }

    int abase = at * 16 + ag * 4;
    partial[(((size_t)z * 8 + kc) * 64 + abase + 0) * 64 + o] = acc0;
    partial[(((size_t)z * 8 + kc) * 64 + abase + 1) * 64 + o] = acc1;
    partial[(((size_t)z * 8 + kc) * 64 + abase + 2) * 64 + o] = acc2;
    partial[(((size_t)z * 8 + kc) * 64 + abase + 3) * 64 + o] = acc3;
}

// finalize: sum partials, abs, mask, sum over a -> s[C]; normalize (ddof=1);
// fc3 + leaky_relu; fc2; sigmoid -> out[z]
__global__ __launch_bounds__(256) void kernel_final(
    const float* __restrict__ partial, const int* __restrict__ mask,
    const float* __restrict__ fc3w, const float* __restrict__ fc2w,
    float* __restrict__ out)
{
    __shared__ float s_red[4][64];
    __shared__ float s_s[64];
    __shared__ float s_sn[64];
    __shared__ float s_t[64];

    int z = blockIdx.x;
    int tid = threadIdx.x;
    int o = tid & 63, ag = tid >> 6;

    const float scale = 1.0f / 80.0f;   // (1/sqrt(H)) * (1/sqrt(N)) = 0.1 * 0.125
    float local = 0.f;
    for (int a = ag; a < 64; a += 4) {
        float y = 0.f;
        #pragma unroll
        for (int kc = 0; kc < 8; ++kc)
            y += partial[(((size_t)z * 8 + kc) * 64 + a) * 64 + o];
        if (mask[z * 64 + a] != 0) local += fabsf(y) * scale;
    }
    s_red[ag][o] = local;
    __syncthreads();

    if (tid < 64) {
        s_s[o] = s_red[0][o] + s_red[1][o] + s_red[2][o] + s_red[3][o];
    }
    __syncthreads();

    if (tid < 64) {
        float mean = 0.f;
        for (int i = 0; i < 64; ++i) mean += s_s[i];
        mean *= (1.0f / 64.0f);
        float var = 0.f;
        for (int i = 0; i < 64; ++i) { float d = s_s[i] - mean; var += d * d; }
        var *= (1.0f / 63.0f);           // ddof=1
        s_sn[o] = (s_s[o] - mean) / (sqrtf(var) + 1e-6f);
    }
    __syncthreads();

    if (tid < 64) {
        float acc = 0.f;
        for (int i = 0; i < 64; ++i) acc += s_sn[i] * fc3w[i * 64 + o];
        acc *= 0.125f;                   // 1/sqrt(C)
        s_t[o] = (acc > 0.f) ? acc : 0.01f * acc;  // leaky_relu
    }
    __syncthreads();

    if (tid == 0) {
        float acc = 0.f;
        for (int i = 0; i < 64; ++i) acc += s_t[i] * fc2w[i];
        acc *= 0.125f;
        out[z] = 1.0f / (1.0f + expf(-acc));
    }
}

extern "C" void kernel_launch(void* const* d_in, const int* in_sizes, int n_in,
                              void* d_out, int out_size, void* d_ws, size_t ws_size,
                              hipStream_t stream) {
    const float* in1  = (const float*)d_in[0];
    const float* in2  = (const float*)d_in[1];
    const float* xyz1 = (const float*)d_in[2];
    const float* xyz2 = (const float*)d_in[3];
    const int*   mask = (const int*)d_in[4];
    const float* w1   = (const float*)d_in[5];
    const float* w2   = (const float*)d_in[6];
    const float* w3   = (const float*)d_in[7];
    const float* fc3w = (const float*)d_in[8];
    const float* fc2w = (const float*)d_in[9];
    float* out = (float*)d_out;

    float* ws      = (float*)d_ws;
    float* xcat    = ws;                       // 32768
    float* rmat    = ws + 32768;               // 32768
    float* h2      = ws + 65536;               // 3276800
    float* M       = ws + 65536 + 3276800;     // 3276800
    float* partial = ws + 65536 + 2 * 3276800; // 262144

    prep_kernel<<<512, 64, 0, stream>>>(in1, in2, xyz1, xyz2, xcat, rmat);
    radial_kernel<<<2048, 256, 0, stream>>>(rmat, w1, w2, h2);
    kernel_M<<<dim3(64, 4), 256, 0, stream>>>(xcat, w3, M);
    kernel_Y<<<dim3(8, 4, 8), 256, 0, stream>>>(h2, M, partial);
    kernel_final<<<8, 256, 0, stream>>>(partial, mask, fc3w, fc2w, out);
}

// Round 2
// 85.749 us; speedup vs baseline: 1.9891x; 1.9891x over previous
//
#include <hip/hip_runtime.h>
#include <math.h>

#define NB 10
#define HH 100
#define TABN 2048
#define TAB_MAX 11.2f

// ---------------------------------------------------------------------------
// Sizes: B=8, N=64, C=64, H=100, R=10
// ws layout (floats):
//   xcat    [8][64][64]          = 32768   @ 0
//   rmat    [8][64][64]          = 32768   @ 32768
//   tab     [TABN+1][100]        = 204900  @ 65536
//   M       [512 zb][6400 ho]    = 3276800 @ 270436
//   partial [16 kc][8 z][64][64] = 524288  @ 3547236
//   s2      [8 z][16 ac][64]     = 8192    @ 4071524
// total ~16.3 MB
// ---------------------------------------------------------------------------

__global__ __launch_bounds__(64) void prep_kernel(
    const float* __restrict__ in1, const float* __restrict__ in2,
    const float* __restrict__ xyz1, const float* __restrict__ xyz2,
    float* __restrict__ xcat, float* __restrict__ rmat)
{
    int zn = blockIdx.x;            // z*64 + n
    int z = zn >> 6, n = zn & 63;
    int t = threadIdx.x;            // 0..63

    xcat[zn * 64 + t] = (n < 32) ? in1[(z * 32 + n) * 64 + t]
                                 : in2[(z * 32 + (n - 32)) * 64 + t];

    float ax, ay, az, bx, by, bz;
    if (n < 32) { const float* p = xyz1 + (z * 32 + n) * 3;        ax = p[0]; ay = p[1]; az = p[2]; }
    else        { const float* p = xyz2 + (z * 32 + (n - 32)) * 3; ax = p[0]; ay = p[1]; az = p[2]; }
    if (t < 32) { const float* p = xyz1 + (z * 32 + t) * 3;        bx = p[0]; by = p[1]; bz = p[2]; }
    else        { const float* p = xyz2 + (z * 32 + (t - 32)) * 3; bx = p[0]; by = p[1]; bz = p[2]; }
    float dx = ax - bx, dy = ay - by, dz = az - bz;
    rmat[zn * 64 + t] = sqrtf(dx * dx + dy * dy + dz * dz + 1e-12f);
}

// Build h2 lookup table: tab[i][c] = h2(i*DELTA)[c], i = 0..TABN inclusive.
// 8 grid points per block, 257 blocks.
__global__ __launch_bounds__(256) void table_kernel(
    const float* __restrict__ w1, const float* __restrict__ w2,
    float* __restrict__ tab)
{
    __shared__ float s_w1[NB * HH];     // 1000
    __shared__ float s_basis[8][NB];
    __shared__ float s_h1[8][HH];

    int tid = threadIdx.x;
    for (int i = tid; i < NB * HH; i += 256) s_w1[i] = w1[i];

    int p0 = blockIdx.x * 8;
    const float DELTA = TAB_MAX / (float)TABN;
    const float STEP = 10.0f / 9.0f;
    const float HALF_PI = 1.57079632679489662f;

    if (tid < 8 * NB) {
        int p = tid / NB, j = tid % NB;
        float r = (float)(p0 + p) * DELTA;
        float u = (r - (float)j * STEP) * (HALF_PI / STEP);
        float c = __cosf(u);
        s_basis[p][j] = (fabsf(u) < HALF_PI) ? c * c : 0.0f;
    }
    __syncthreads();

    const float inv_sqrt10 = 0.31622776601683794f;
    for (int task = tid; task < 8 * HH; task += 256) {
        int p = task / HH, k = task % HH;
        float acc = 0.f;
        #pragma unroll
        for (int j = 0; j < NB; ++j) acc += s_basis[p][j] * s_w1[j * HH + k];
        acc *= inv_sqrt10;
        float sg = 1.0f / (1.0f + __expf(-acc));
        s_h1[p][k] = acc * sg;
    }
    __syncthreads();

    if (tid < 8 * 25) {
        int p = tid / 25, k2g = tid % 25;
        int idx = p0 + p;
        float4 acc = make_float4(0.f, 0.f, 0.f, 0.f);
        const float4* w2c = (const float4*)(w2 + k2g * 4);
        #pragma unroll 4
        for (int k = 0; k < HH; ++k) {
            float hv = s_h1[p][k];
            float4 wv = *(const float4*)(w2 + (size_t)k * HH + k2g * 4);
            acc.x += hv * wv.x; acc.y += hv * wv.y; acc.z += hv * wv.z; acc.w += hv * wv.w;
        }
        (void)w2c;
        if (idx <= TABN) {
            float4 o;
            float a;
            a = acc.x * 0.1f; o.x = a / (1.0f + __expf(-a));
            a = acc.y * 0.1f; o.y = a / (1.0f + __expf(-a));
            a = acc.z * 0.1f; o.z = a / (1.0f + __expf(-a));
            a = acc.w * 0.1f; o.w = a / (1.0f + __expf(-a));
            *(float4*)(tab + (size_t)idx * HH + k2g * 4) = o;
        }
    }
}

// M[zb][h*64+o] = sum_i w3[h][o*64+i] * xcat[zb][i]
// grid (64 zb-groups of 8, 25 ho-chunks of 256), 256 threads -> 1 ho/thread
__global__ __launch_bounds__(256, 4) void kernel_M(
    const float* __restrict__ xcat, const float* __restrict__ w3,
    float* __restrict__ Mout)
{
    __shared__ float s_x[8][64];
    int tid = threadIdx.x;
    int zb0 = blockIdx.x * 8;
    for (int i = tid; i < 128; i += 256)
        ((float4*)s_x)[i] = ((const float4*)(xcat + zb0 * 64))[i];
    __syncthreads();

    int ho = blockIdx.y * 256 + tid;
    int h = ho >> 6, o = ho & 63;
    const float4* wrow = (const float4*)(w3 + (size_t)h * 4096 + o * 64);
    const float4* sx4 = (const float4*)s_x;   // sx4[zb*16 + i4]

    float a0 = 0, a1 = 0, a2 = 0, a3 = 0, a4 = 0, a5 = 0, a6 = 0, a7 = 0;
    #pragma unroll
    for (int i4 = 0; i4 < 16; ++i4) {
        float4 w = wrow[i4];
        float4 x0 = sx4[0 * 16 + i4];
        float4 x1 = sx4[1 * 16 + i4];
        float4 x2 = sx4[2 * 16 + i4];
        float4 x3 = sx4[3 * 16 + i4];
        a0 += w.x * x0.x + w.y * x0.y + w.z * x0.z + w.w * x0.w;
        a1 += w.x * x1.x + w.y * x1.y + w.z * x1.z + w.w * x1.w;
        a2 += w.x * x2.x + w.y * x2.y + w.z * x2.z + w.w * x2.w;
        a3 += w.x * x3.x + w.y * x3.y + w.z * x3.z + w.w * x3.w;
        float4 x4 = sx4[4 * 16 + i4];
        float4 x5 = sx4[5 * 16 + i4];
        float4 x6 = sx4[6 * 16 + i4];
        float4 x7 = sx4[7 * 16 + i4];
        a4 += w.x * x4.x + w.y * x4.y + w.z * x4.z + w.w * x4.w;
        a5 += w.x * x5.x + w.y * x5.y + w.z * x5.z + w.w * x5.w;
        a6 += w.x * x6.x + w.y * x6.y + w.z * x6.z + w.w * x6.w;
        a7 += w.x * x7.x + w.y * x7.y + w.z * x7.z + w.w * x7.w;
    }
    Mout[(size_t)(zb0 + 0) * 6400 + ho] = a0;
    Mout[(size_t)(zb0 + 1) * 6400 + ho] = a1;
    Mout[(size_t)(zb0 + 2) * 6400 + ho] = a2;
    Mout[(size_t)(zb0 + 3) * 6400 + ho] = a3;
    Mout[(size_t)(zb0 + 4) * 6400 + ho] = a4;
    Mout[(size_t)(zb0 + 5) * 6400 + ho] = a5;
    Mout[(size_t)(zb0 + 6) * 6400 + ho] = a6;
    Mout[(size_t)(zb0 + 7) * 6400 + ho] = a7;
}

// y partials with fused table-lerp h2.
// grid (8 z, 2 at[32 a], 16 kc[4 b]), 256 threads = 16 og x 16 ar
// thread computes 2 a-rows x 4 o-cols.
__global__ __launch_bounds__(256, 4) void kernel_Y(
    const float* __restrict__ rmat, const float* __restrict__ tab,
    const float* __restrict__ M, float* __restrict__ partial)
{
    __shared__ float s_M[100][64];    // 25.6 KB
    __shared__ float s_h2[32][100];   // 12.8 KB

    int z = blockIdx.x, at = blockIdx.y, kc = blockIdx.z;
    int tid = threadIdx.x;
    int og = tid & 15;       // o = og*4 .. og*4+3
    int ar = tid >> 4;       // la = 2*ar, 2*ar+1

    const float INV_DELTA = (float)TABN / TAB_MAX;

    float4 acc0 = make_float4(0.f, 0.f, 0.f, 0.f);
    float4 acc1 = make_float4(0.f, 0.f, 0.f, 0.f);

    for (int sc = 0; sc < 4; ++sc) {
        int b = kc * 4 + sc;
        __syncthreads();
        // stage M[h][o] for this (z,b)
        const float* Msrc = M + ((size_t)(z * 64 + b)) * 6400;
        for (int idx = tid; idx < 6400; idx += 256)
            s_M[idx >> 6][idx & 63] = Msrc[idx];
        // stage h2 via table lerp: 32 a-rows x 100 comps
        for (int idx = tid; idx < 3200; idx += 256) {
            int la = idx / 100, c = idx - la * 100;
            float r = rmat[(size_t)(z * 64 + at * 32 + la) * 64 + b];
            float t = r * INV_DELTA;
            int i0 = (int)t;
            i0 = (i0 < TABN - 1) ? i0 : (TABN - 1);
            float f = t - (float)i0;
            f = (f < 1.0f) ? f : 1.0f;
            float v = tab[(size_t)i0 * HH + c];
            float v2 = tab[(size_t)i0 * HH + HH + c];
            s_h2[la][c] = fmaf(f, v2 - v, v);
        }
        __syncthreads();

        #pragma unroll 4
        for (int c = 0; c < 100; ++c) {
            float4 mv = *(const float4*)&s_M[c][og * 4];
            float h0 = s_h2[2 * ar][c];
            float h1 = s_h2[2 * ar + 1][c];
            acc0.x += h0 * mv.x; acc0.y += h0 * mv.y; acc0.z += h0 * mv.z; acc0.w += h0 * mv.w;
            acc1.x += h1 * mv.x; acc1.y += h1 * mv.y; acc1.z += h1 * mv.z; acc1.w += h1 * mv.w;
        }
    }

    size_t pb = ((size_t)(kc * 8 + z)) * 4096 + (size_t)(at * 32 + 2 * ar) * 64 + og * 4;
    *(float4*)&partial[pb] = acc0;
    *(float4*)&partial[pb + 64] = acc1;
}

// reduce partials over kc, abs+mask+scale, partial-sum over 4 a-rows
// grid (8 z, 16 ac), 256 threads
__global__ __launch_bounds__(256) void kernel_red(
    const float* __restrict__ partial, const int* __restrict__ mask,
    float* __restrict__ s2)
{
    __shared__ float sred[4][64];
    int z = blockIdx.x, ac = blockIdx.y;
    int tid = threadIdx.x;
    int o = tid & 63, ar = tid >> 6;
    int a = ac * 4 + ar;

    float val = 0.f;
    #pragma unroll
    for (int kc = 0; kc < 16; ++kc)
        val += partial[((size_t)(kc * 8 + z)) * 4096 + (size_t)a * 64 + o];

    const float scale = 0.0125f;   // (1/sqrt(100)) * (1/sqrt(64))
    float m = (mask[z * 64 + a] != 0) ? 1.0f : 0.0f;
    sred[ar][o] = fabsf(val) * scale * m;
    __syncthreads();

    if (tid < 64)
        s2[((size_t)z * 16 + ac) * 64 + o] = sred[0][o] + sred[1][o] + sred[2][o] + sred[3][o];
}

// per-z finalize: sum s2 over ac, normalize (ddof=1), fc3+leaky, fc2, sigmoid
__global__ __launch_bounds__(64) void kernel_final(
    const float* __restrict__ s2, const float* __restrict__ fc3w,
    const float* __restrict__ fc2w, float* __restrict__ out)
{
    __shared__ float s_sn[64];
    int z = blockIdx.x;
    int o = threadIdx.x;   // 0..63, one wave

    float s = 0.f;
    #pragma unroll
    for (int ac = 0; ac < 16; ++ac)
        s += s2[((size_t)z * 16 + ac) * 64 + o];

    float tot = s;
    #pragma unroll
    for (int d = 32; d >= 1; d >>= 1) tot += __shfl_xor(tot, d, 64);
    float mean = tot * (1.0f / 64.0f);
    float dv = s - mean;
    float v2 = dv * dv;
    #pragma unroll
    for (int d = 32; d >= 1; d >>= 1) v2 += __shfl_xor(v2, d, 64);
    float var = v2 * (1.0f / 63.0f);
    float sn = dv / (sqrtf(var) + 1e-6f);

    s_sn[o] = sn;
    __syncthreads();

    float acc = 0.f;
    #pragma unroll 8
    for (int i = 0; i < 64; ++i) acc += s_sn[i] * fc3w[i * 64 + o];
    acc *= 0.125f;
    float t = (acc > 0.f) ? acc : 0.01f * acc;

    float pr = t * fc2w[o];
    #pragma unroll
    for (int d = 32; d >= 1; d >>= 1) pr += __shfl_xor(pr, d, 64);
    if (o == 0) out[z] = 1.0f / (1.0f + expf(-0.125f * pr));
}

extern "C" void kernel_launch(void* const* d_in, const int* in_sizes, int n_in,
                              void* d_out, int out_size, void* d_ws, size_t ws_size,
                              hipStream_t stream) {
    const float* in1  = (const float*)d_in[0];
    const float* in2  = (const float*)d_in[1];
    const float* xyz1 = (const float*)d_in[2];
    const float* xyz2 = (const float*)d_in[3];
    const int*   mask = (const int*)d_in[4];
    const float* w1   = (const float*)d_in[5];
    const float* w2   = (const float*)d_in[6];
    const float* w3   = (const float*)d_in[7];
    const float* fc3w = (const float*)d_in[8];
    const float* fc2w = (const float*)d_in[9];
    float* out = (float*)d_out;

    float* ws      = (float*)d_ws;
    float* xcat    = ws;                  // 32768
    float* rmat    = ws + 32768;          // 32768
    float* tab     = ws + 65536;          // 204900
    float* M       = ws + 270436;         // 3276800
    float* partial = ws + 3547236;        // 524288
    float* s2      = ws + 4071524;        // 8192

    prep_kernel<<<512, 64, 0, stream>>>(in1, in2, xyz1, xyz2, xcat, rmat);
    table_kernel<<<257, 256, 0, stream>>>(w1, w2, tab);
    kernel_M<<<dim3(64, 25), 256, 0, stream>>>(xcat, w3, M);
    kernel_Y<<<dim3(8, 2, 16), 256, 0, stream>>>(rmat, tab, M, partial);
    kernel_red<<<dim3(8, 16), 256, 0, stream>>>(partial, mask, s2);
    kernel_final<<<8, 64, 0, stream>>>(s2, fc3w, fc2w, out);
}

// Round 3
// 54.869 us; speedup vs baseline: 3.1085x; 1.5628x over previous
//
#include <hip/hip_runtime.h>
#include <math.h>

#define NB 10
#define HH 100
#define TABN 2048
#define TAB_MAX 11.2f
#define INV_DELTA ((float)TABN / TAB_MAX)

// ---------------------------------------------------------------------------
// Sizes: B=8, N=64, C=64, H=100, R=10
// ws layout (floats):
//   tab     [2049][100]           = 204900   @ 0
//   M       [512 zb][6400 ho]     = 3276800  @ 204900
//   partial [64 b][8 z][64a][64o] = 2097152  @ 3481700
//   s2      [8 z][16 ac][64]      = 8192     @ 5578852
// total ~22.3 MB
// ---------------------------------------------------------------------------

// Fused: blocks 0..256 build the h2 lookup table; blocks 257..480 build M.
// M[zb][h*64+o] = sum_i w3[h][o*64+i] * x[zb][i], x = concat(in1,in2) read directly.
__global__ __launch_bounds__(256) void tm_kernel(
    const float* __restrict__ in1, const float* __restrict__ in2,
    const float* __restrict__ w1, const float* __restrict__ w2,
    const float* __restrict__ w3,
    float* __restrict__ tab, float* __restrict__ Mout)
{
    __shared__ float s_w1[NB * HH];
    __shared__ float s_basis[8][NB];
    __shared__ float s_h1[8][HH];
    __shared__ float s_x[16][64];

    int tid = threadIdx.x;

    if (blockIdx.x < 257) {
        // ------------------- table path -------------------
        for (int i = tid; i < NB * HH; i += 256) s_w1[i] = w1[i];

        int p0 = blockIdx.x * 8;
        const float DELTA = TAB_MAX / (float)TABN;
        const float STEP = 10.0f / 9.0f;
        const float HALF_PI = 1.57079632679489662f;

        if (tid < 8 * NB) {
            int p = tid / NB, j = tid % NB;
            float r = (float)(p0 + p) * DELTA;
            float u = (r - (float)j * STEP) * (HALF_PI / STEP);
            float c = __cosf(u);
            s_basis[p][j] = (fabsf(u) < HALF_PI) ? c * c : 0.0f;
        }
        __syncthreads();

        const float inv_sqrt10 = 0.31622776601683794f;
        for (int task = tid; task < 8 * HH; task += 256) {
            int p = task / HH, k = task % HH;
            float acc = 0.f;
            #pragma unroll
            for (int j = 0; j < NB; ++j) acc += s_basis[p][j] * s_w1[j * HH + k];
            acc *= inv_sqrt10;
            float sg = 1.0f / (1.0f + __expf(-acc));
            s_h1[p][k] = acc * sg;
        }
        __syncthreads();

        if (tid < 8 * 25) {
            int p = tid / 25, k2g = tid % 25;
            int idx = p0 + p;
            float4 acc = make_float4(0.f, 0.f, 0.f, 0.f);
            #pragma unroll 4
            for (int k = 0; k < HH; ++k) {
                float hv = s_h1[p][k];
                float4 wv = *(const float4*)(w2 + (size_t)k * HH + k2g * 4);
                acc.x += hv * wv.x; acc.y += hv * wv.y; acc.z += hv * wv.z; acc.w += hv * wv.w;
            }
            if (idx <= TABN) {
                float4 o; float a;
                a = acc.x * 0.1f; o.x = a / (1.0f + __expf(-a));
                a = acc.y * 0.1f; o.y = a / (1.0f + __expf(-a));
                a = acc.z * 0.1f; o.z = a / (1.0f + __expf(-a));
                a = acc.w * 0.1f; o.w = a / (1.0f + __expf(-a));
                *(float4*)(tab + (size_t)idx * HH + k2g * 4) = o;
            }
        }
    } else {
        // ------------------- M path -------------------
        int m = blockIdx.x - 257;          // 0..223
        int zbg = m / 7, yc = m % 7;       // 32 zb-groups of 16, 7 task-chunks

        {
            int lz = tid >> 4, q = tid & 15;
            int zb = zbg * 16 + lz;
            int z = zb >> 6, b = zb & 63;
            const float* src = (b < 32) ? (in1 + (size_t)(z * 32 + b) * 64)
                                        : (in2 + (size_t)(z * 32 + (b - 32)) * 64);
            *(float4*)&s_x[lz][q * 4] = *(const float4*)(src + q * 4);
        }
        __syncthreads();

        int task = yc * 256 + tid;         // (h, og): 1600 tasks
        if (task < 1600) {
            int h = task >> 4, og = task & 15;
            const float* wbase = w3 + (size_t)h * 4096 + og * 4 * 64;

            float4 acc[16];
            #pragma unroll
            for (int l = 0; l < 16; ++l) acc[l] = make_float4(0.f, 0.f, 0.f, 0.f);

            const float4* sx4 = (const float4*)s_x;
            #pragma unroll 2
            for (int i4 = 0; i4 < 16; ++i4) {
                float4 wa = *(const float4*)(wbase + 0 * 64 + i4 * 4);
                float4 wb = *(const float4*)(wbase + 1 * 64 + i4 * 4);
                float4 wc = *(const float4*)(wbase + 2 * 64 + i4 * 4);
                float4 wd = *(const float4*)(wbase + 3 * 64 + i4 * 4);
                #pragma unroll
                for (int l = 0; l < 16; ++l) {
                    float4 xv = sx4[l * 16 + i4];
                    acc[l].x += wa.x * xv.x + wa.y * xv.y + wa.z * xv.z + wa.w * xv.w;
                    acc[l].y += wb.x * xv.x + wb.y * xv.y + wb.z * xv.z + wb.w * xv.w;
                    acc[l].z += wc.x * xv.x + wc.y * xv.y + wc.z * xv.z + wc.w * xv.w;
                    acc[l].w += wd.x * xv.x + wd.y * xv.y + wd.z * xv.z + wd.w * xv.w;
                }
            }
            #pragma unroll
            for (int l = 0; l < 16; ++l) {
                int zb = zbg * 16 + l;
                *(float4*)(Mout + (size_t)zb * 6400 + h * 64 + og * 4) = acc[l];
            }
        }
    }
}

// y partial per (z,b): out tile 64a x 64o, thread = 4a x 4o.
// h2 staged TRANSPOSED [c][a] with XOR swizzle on the 16B granule.
__global__ __launch_bounds__(256) void kernel_Y(
    const float* __restrict__ xyz1, const float* __restrict__ xyz2,
    const float* __restrict__ tab, const float* __restrict__ M,
    float* __restrict__ partial)
{
    __shared__ float s_M[100 * 64];     // 25.6 KB
    __shared__ float s_h2T[100 * 64];   // 25.6 KB, [c][a] swizzled
    __shared__ int   s_i0[64];
    __shared__ float s_f[64];

    int z = blockIdx.x, b = blockIdx.y;
    int tid = threadIdx.x;

    if (tid < 64) {
        int a = tid;
        const float* pa = (a < 32) ? (xyz1 + (size_t)(z * 32 + a) * 3)
                                   : (xyz2 + (size_t)(z * 32 + (a - 32)) * 3);
        const float* pb = (b < 32) ? (xyz1 + (size_t)(z * 32 + b) * 3)
                                   : (xyz2 + (size_t)(z * 32 + (b - 32)) * 3);
        float dx = pa[0] - pb[0], dy = pa[1] - pb[1], dz = pa[2] - pb[2];
        float r = sqrtf(dx * dx + dy * dy + dz * dz + 1e-12f);
        float t = r * INV_DELTA;
        int i0 = (int)t;
        i0 = (i0 < TABN - 1) ? i0 : (TABN - 1);
        float f = t - (float)i0;
        s_i0[a] = i0;
        s_f[a] = (f < 1.0f) ? f : 1.0f;
    }

    // stage M[h][o] for this (z,b)
    {
        const float4* Msrc = (const float4*)(M + (size_t)(z * 64 + b) * 6400);
        float4* sM4 = (float4*)s_M;
        for (int i = tid; i < 1600; i += 256) sM4[i] = Msrc[i];
    }
    __syncthreads();

    // lerp h2 transposed: task = (a4, c); lanes walk c (coalesced tab reads)
    for (int task = tid; task < 1600; task += 256) {
        int a4 = task / 100, c = task - a4 * 100;
        float4 hv;
        #pragma unroll
        for (int k = 0; k < 4; ++k) {
            int a = a4 * 4 + k;
            int i0 = s_i0[a];
            float f = s_f[a];
            float v0 = tab[(size_t)i0 * HH + c];
            float v1 = tab[(size_t)i0 * HH + HH + c];
            ((float*)&hv)[k] = fmaf(f, v1 - v0, v0);
        }
        *(float4*)&s_h2T[c * 64 + ((a4 ^ (c & 7)) << 2)] = hv;
    }
    __syncthreads();

    int og = tid & 15, ag = tid >> 4;
    float4 acc0 = make_float4(0.f, 0.f, 0.f, 0.f);
    float4 acc1 = make_float4(0.f, 0.f, 0.f, 0.f);
    float4 acc2 = make_float4(0.f, 0.f, 0.f, 0.f);
    float4 acc3 = make_float4(0.f, 0.f, 0.f, 0.f);

    #pragma unroll 4
    for (int c = 0; c < 100; ++c) {
        float4 mv = *(const float4*)&s_M[c * 64 + og * 4];
        float4 hv = *(const float4*)&s_h2T[c * 64 + ((ag ^ (c & 7)) << 2)];
        acc0.x += hv.x * mv.x; acc0.y += hv.x * mv.y; acc0.z += hv.x * mv.z; acc0.w += hv.x * mv.w;
        acc1.x += hv.y * mv.x; acc1.y += hv.y * mv.y; acc1.z += hv.y * mv.z; acc1.w += hv.y * mv.w;
        acc2.x += hv.z * mv.x; acc2.y += hv.z * mv.y; acc2.z += hv.z * mv.z; acc2.w += hv.z * mv.w;
        acc3.x += hv.w * mv.x; acc3.y += hv.w * mv.y; acc3.z += hv.w * mv.z; acc3.w += hv.w * mv.w;
    }

    size_t base = ((size_t)(b * 8 + z) * 64 + ag * 4) * 64 + og * 4;
    *(float4*)&partial[base]       = acc0;
    *(float4*)&partial[base + 64]  = acc1;
    *(float4*)&partial[base + 128] = acc2;
    *(float4*)&partial[base + 192] = acc3;
}

// reduce partials over b, abs+mask+scale, partial-sum 4 a-rows -> s2
__global__ __launch_bounds__(256) void kernel_red(
    const float* __restrict__ partial, const int* __restrict__ mask,
    float* __restrict__ s2)
{
    __shared__ float sred[4][64];
    int z = blockIdx.x, ac = blockIdx.y;
    int tid = threadIdx.x;
    int o = tid & 63, ar = tid >> 6;
    int a = ac * 4 + ar;

    float val = 0.f;
    #pragma unroll 8
    for (int b = 0; b < 64; ++b)
        val += partial[((size_t)(b * 8 + z) * 64 + a) * 64 + o];

    const float scale = 0.0125f;   // (1/sqrt(100)) * (1/sqrt(64))
    float m = (mask[z * 64 + a] != 0) ? 1.0f : 0.0f;
    sred[ar][o] = fabsf(val) * scale * m;
    __syncthreads();

    if (tid < 64)
        s2[((size_t)z * 16 + ac) * 64 + o] = sred[0][o] + sred[1][o] + sred[2][o] + sred[3][o];
}

// per-z finalize: sum s2 over ac, normalize (ddof=1), fc3+leaky, fc2, sigmoid
__global__ __launch_bounds__(64) void kernel_final(
    const float* __restrict__ s2, const float* __restrict__ fc3w,
    const float* __restrict__ fc2w, float* __restrict__ out)
{
    __shared__ float s_sn[64];
    int z = blockIdx.x;
    int o = threadIdx.x;   // one wave

    float s = 0.f;
    #pragma unroll
    for (int ac = 0; ac < 16; ++ac)
        s += s2[((size_t)z * 16 + ac) * 64 + o];

    float tot = s;
    #pragma unroll
    for (int d = 32; d >= 1; d >>= 1) tot += __shfl_xor(tot, d, 64);
    float mean = tot * (1.0f / 64.0f);
    float dv = s - mean;
    float v2 = dv * dv;
    #pragma unroll
    for (int d = 32; d >= 1; d >>= 1) v2 += __shfl_xor(v2, d, 64);
    float var = v2 * (1.0f / 63.0f);
    float sn = dv / (sqrtf(var) + 1e-6f);

    s_sn[o] = sn;
    __syncthreads();

    float acc = 0.f;
    #pragma unroll 8
    for (int i = 0; i < 64; ++i) acc += s_sn[i] * fc3w[i * 64 + o];
    acc *= 0.125f;
    float t = (acc > 0.f) ? acc : 0.01f * acc;

    float pr = t * fc2w[o];
    #pragma unroll
    for (int d = 32; d >= 1; d >>= 1) pr += __shfl_xor(pr, d, 64);
    if (o == 0) out[z] = 1.0f / (1.0f + expf(-0.125f * pr));
}

extern "C" void kernel_launch(void* const* d_in, const int* in_sizes, int n_in,
                              void* d_out, int out_size, void* d_ws, size_t ws_size,
                              hipStream_t stream) {
    const float* in1  = (const float*)d_in[0];
    const float* in2  = (const float*)d_in[1];
    const float* xyz1 = (const float*)d_in[2];
    const float* xyz2 = (const float*)d_in[3];
    const int*   mask = (const int*)d_in[4];
    const float* w1   = (const float*)d_in[5];
    const float* w2   = (const float*)d_in[6];
    const float* w3   = (const float*)d_in[7];
    const float* fc3w = (const float*)d_in[8];
    const float* fc2w = (const float*)d_in[9];
    float* out = (float*)d_out;

    float* ws      = (float*)d_ws;
    float* tab     = ws;                  // 204900
    float* M       = ws + 204900;         // 3276800
    float* partial = ws + 3481700;        // 2097152
    float* s2      = ws + 5578852;        // 8192

    tm_kernel<<<481, 256, 0, stream>>>(in1, in2, w1, w2, w3, tab, M);
    kernel_Y<<<dim3(8, 64), 256, 0, stream>>>(xyz1, xyz2, tab, M, partial);
    kernel_red<<<dim3(8, 16), 256, 0, stream>>>(partial, mask, s2);
    kernel_final<<<8, 64, 0, stream>>>(s2, fc3w, fc2w, out);
}